// Round 1
// baseline (530.486 us; speedup 1.0000x reference)
//
#include <hip/hip_runtime.h>
#include <math.h>

// ---------------------------------------------------------------------------
// GATv2 x2 + mean-pool + linear, MI355X.
// Strategy: build CSR by dst once per launch (reused by both layers), then
// per-layer: dual GEMM (xl,xr) -> per-dst wave online-softmax aggregation
// (no output atomics), then run-length pooled mean + tiny final GEMM.
// ---------------------------------------------------------------------------

// ---------------- CSR build ----------------
__global__ __launch_bounds__(256) void count_deg_kernel(
    const int* __restrict__ dst, int* __restrict__ deg, int E) {
    int e = blockIdx.x * blockDim.x + threadIdx.x;
    if (e < E) atomicAdd(&deg[dst[e]], 1);
}

__global__ __launch_bounds__(1024) void exscan_kernel(
    const int* __restrict__ deg, int* __restrict__ rowptr, int n) {
    __shared__ int buf[1024];
    __shared__ int carry;
    int t = threadIdx.x;
    if (t == 0) { carry = 0; rowptr[0] = 0; }
    __syncthreads();
    for (int base = 0; base < n; base += 1024) {
        int i = base + t;
        buf[t] = (i < n) ? deg[i] : 0;
        __syncthreads();
        // Hillis-Steele inclusive scan
        for (int off = 1; off < 1024; off <<= 1) {
            int x = (t >= off) ? buf[t - off] : 0;
            __syncthreads();
            buf[t] += x;
            __syncthreads();
        }
        if (i < n) rowptr[i + 1] = buf[t] + carry;
        __syncthreads();
        if (t == 1023) carry += buf[1023];
        __syncthreads();
    }
}

__global__ __launch_bounds__(256) void fill_csr_kernel(
    const int* __restrict__ src, const int* __restrict__ dst,
    const int* __restrict__ rowptr, int* __restrict__ fill,
    int* __restrict__ csr_src, int E) {
    int e = blockIdx.x * blockDim.x + threadIdx.x;
    if (e < E) {
        int d = dst[e];
        int pos = atomicAdd(&fill[d], 1);
        csr_src[rowptr[d] + pos] = src[e];
    }
}

// ---------------- dual GEMM: xl = X*Wl + bl, xr = X*Wr + br ----------------
// X: [n,64] row-major, W: [64,64] row-major. 16 rows per block, 256 threads.
#define GROWS 16
__global__ __launch_bounds__(256) void dual_gemm64_kernel(
    const float* __restrict__ X,
    const float* __restrict__ Wl, const float* __restrict__ bl,
    const float* __restrict__ Wr, const float* __restrict__ br,
    float* __restrict__ xl, float* __restrict__ xr, int n) {
    __shared__ float WlS[64 * 64];
    __shared__ float WrS[64 * 64];
    __shared__ float xS[GROWS * 64];
    int t = threadIdx.x;
    for (int i = t; i < 4096; i += 256) { WlS[i] = Wl[i]; WrS[i] = Wr[i]; }
    int row0 = blockIdx.x * GROWS;
    for (int i = t; i < GROWS * 64; i += 256) {
        int r = row0 + (i >> 6);
        xS[i] = (r < n) ? X[r * 64 + (i & 63)] : 0.f;
    }
    __syncthreads();
    int h  = t & 63;   // output column (lane)
    int rb = t >> 6;   // 0..3
    float accl[4] = {0.f, 0.f, 0.f, 0.f};
    float accr[4] = {0.f, 0.f, 0.f, 0.f};
    for (int d = 0; d < 64; ++d) {
        float wl = WlS[d * 64 + h];
        float wr = WrS[d * 64 + h];
#pragma unroll
        for (int i = 0; i < 4; ++i) {
            float xv = xS[(rb + 4 * i) * 64 + d];  // wave-uniform -> broadcast
            accl[i] += xv * wl;
            accr[i] += xv * wr;
        }
    }
    float blv = bl[h], brv = br[h];
#pragma unroll
    for (int i = 0; i < 4; ++i) {
        int r = row0 + rb + 4 * i;
        if (r < n) {
            xl[r * 64 + h] = accl[i] + blv;
            xr[r * 64 + h] = accr[i] + brv;
        }
    }
}

// ---------------- per-dst GATv2 aggregation, online softmax ----------------
// one wave (64 lanes) per destination node; lane = feature dim.
__global__ __launch_bounds__(256) void gat_aggregate_kernel(
    const float* __restrict__ xl, const float* __restrict__ xr,
    const int* __restrict__ rowptr, const int* __restrict__ csr_src,
    const float* __restrict__ att, const float* __restrict__ bias,
    float* __restrict__ out, int n) {
    int wid  = (blockIdx.x * blockDim.x + threadIdx.x) >> 6;
    int lane = threadIdx.x & 63;
    if (wid >= n) return;
    int d = wid;
    float xr_d  = xr[d * 64 + lane];
    float att_l = att[lane];
    int beg = rowptr[d], end = rowptr[d + 1];
    float m = -INFINITY, s = 0.f, acc = 0.f;
    for (int p = beg; p < end; ++p) {
        int srcn  = csr_src[p];          // wave-uniform
        float xls = xl[srcn * 64 + lane];
        float z   = xls + xr_d;
        float zl  = (z > 0.f) ? z : 0.2f * z;  // leaky_relu(0.2)
        float c   = zl * att_l;
        // 64-lane reduce
        c += __shfl_xor(c, 32);
        c += __shfl_xor(c, 16);
        c += __shfl_xor(c, 8);
        c += __shfl_xor(c, 4);
        c += __shfl_xor(c, 2);
        c += __shfl_xor(c, 1);
        float e  = c;
        float mn = fmaxf(m, e);
        float ra = __expf(m - mn);   // 0 on first edge (m=-inf)
        float cb = __expf(e - mn);
        s   = s * ra + cb;
        acc = acc * ra + cb * xls;
        m   = mn;
    }
    float val = (s > 0.f) ? (acc / s) : 0.f;  // deg-0 node -> 0 (+bias)
    val += bias[lane];
    out[d * 64 + lane] = fmaxf(val, 0.f);     // outer relu
}

// ---------------- mean pool over sorted batch ----------------
__global__ __launch_bounds__(256) void pool_kernel(
    const float* __restrict__ h, const int* __restrict__ batch,
    float* __restrict__ sums, float* __restrict__ cnts, int n, int nwaves) {
    int wid  = (blockIdx.x * blockDim.x + threadIdx.x) >> 6;
    int lane = threadIdx.x & 63;
    int per   = (n + nwaves - 1) / nwaves;
    int start = wid * per;
    int end   = min(n, start + per);
    if (start >= end) return;
    int cur   = batch[start];
    float acc = 0.f, cnt = 0.f;
    for (int i = start; i < end; ++i) {
        int g = batch[i];   // wave-uniform
        if (g != cur) {
            atomicAdd(&sums[cur * 64 + lane], acc);
            if (lane == 0) atomicAdd(&cnts[cur], cnt);
            acc = 0.f; cnt = 0.f; cur = g;
        }
        acc += h[i * 64 + lane];
        cnt += 1.f;
    }
    atomicAdd(&sums[cur * 64 + lane], acc);
    if (lane == 0) atomicAdd(&cnts[cur], cnt);
}

// ---------------- final: out = (sums/cnt) @ lin_w + lin_b ----------------
__global__ __launch_bounds__(256) void final_kernel(
    const float* __restrict__ sums, const float* __restrict__ cnts,
    const float* __restrict__ lin_w, const float* __restrict__ lin_b,
    float* __restrict__ out, int total) {
    int tid = blockIdx.x * blockDim.x + threadIdx.x;
    if (tid >= total) return;
    int g = tid >> 5, o = tid & 31;
    float inv = 1.f / fmaxf(cnts[g], 1.f);
    float a = 0.f;
    for (int h = 0; h < 64; ++h) a += sums[g * 64 + h] * lin_w[h * 32 + o];
    out[tid] = a * inv + lin_b[o];
}

extern "C" void kernel_launch(void* const* d_in, const int* in_sizes, int n_in,
                              void* d_out, int out_size, void* d_ws, size_t ws_size,
                              hipStream_t stream) {
    const float* x     = (const float*)d_in[0];
    const int*   ei    = (const int*)d_in[1];
    const int*   batch = (const int*)d_in[2];
    const float* Wl1   = (const float*)d_in[3];
    const float* bl1   = (const float*)d_in[4];
    const float* Wr1   = (const float*)d_in[5];
    const float* br1   = (const float*)d_in[6];
    const float* att1  = (const float*)d_in[7];
    const float* bias1 = (const float*)d_in[8];
    const float* Wl2   = (const float*)d_in[9];
    const float* bl2   = (const float*)d_in[10];
    const float* Wr2   = (const float*)d_in[11];
    const float* br2   = (const float*)d_in[12];
    const float* att2  = (const float*)d_in[13];
    const float* bias2 = (const float*)d_in[14];
    const float* lin_w = (const float*)d_in[15];
    const float* lin_b = (const float*)d_in[16];
    float* out = (float*)d_out;

    const int N = in_sizes[0] / 64;
    const int E = in_sizes[1] / 2;
    const int G = out_size / 32;
    const int* src = ei;
    const int* dst = ei + E;

    // ---- workspace carve-up (256B-aligned) ----
    char*  ws  = (char*)d_ws;
    size_t off = 0;
    auto alloc = [&](size_t bytes) -> void* {
        void* p = ws + off;
        off += bytes;
        off = (off + 255) & ~(size_t)255;
        return p;
    };
    float* xl      = (float*)alloc((size_t)N * 64 * sizeof(float));
    float* xr      = (float*)alloc((size_t)N * 64 * sizeof(float));
    float* h1      = (float*)alloc((size_t)N * 64 * sizeof(float));
    float* h2      = (float*)alloc((size_t)N * 64 * sizeof(float));
    float* sums    = (float*)alloc((size_t)G * 64 * sizeof(float));
    float* cnts    = (float*)alloc((size_t)G * sizeof(float));
    int*   deg     = (int*)alloc((size_t)N * sizeof(int));
    int*   fill    = (int*)alloc((size_t)N * sizeof(int));
    int*   rowptr  = (int*)alloc((size_t)(N + 1) * sizeof(int));
    int*   csr_src = (int*)alloc((size_t)E * sizeof(int));

    // ---- zero what needs zeroing (ws is poisoned 0xAA each call) ----
    hipMemsetAsync(deg,  0, (size_t)N * sizeof(int), stream);
    hipMemsetAsync(fill, 0, (size_t)N * sizeof(int), stream);
    hipMemsetAsync(sums, 0, (size_t)G * 64 * sizeof(float), stream);
    hipMemsetAsync(cnts, 0, (size_t)G * sizeof(float), stream);

    // ---- CSR build (shared by both layers) ----
    int egrid = (E + 255) / 256;
    count_deg_kernel<<<egrid, 256, 0, stream>>>(dst, deg, E);
    exscan_kernel<<<1, 1024, 0, stream>>>(deg, rowptr, N);
    fill_csr_kernel<<<egrid, 256, 0, stream>>>(src, dst, rowptr, fill, csr_src, E);

    int ggrid = (N + GROWS - 1) / GROWS;
    int agrid = (N + 3) / 4;          // 4 waves/block, 1 wave per dst node

    // ---- layer 1 ----
    dual_gemm64_kernel<<<ggrid, 256, 0, stream>>>(x, Wl1, bl1, Wr1, br1, xl, xr, N);
    gat_aggregate_kernel<<<agrid, 256, 0, stream>>>(xl, xr, rowptr, csr_src, att1, bias1, h1, N);

    // ---- layer 2 ----
    dual_gemm64_kernel<<<ggrid, 256, 0, stream>>>(h1, Wl2, bl2, Wr2, br2, xl, xr, N);
    gat_aggregate_kernel<<<agrid, 256, 0, stream>>>(xl, xr, rowptr, csr_src, att2, bias2, h2, N);

    // ---- pool + final linear ----
    const int NWAVES = 1024;                    // 256 blocks * 4 waves
    pool_kernel<<<256, 256, 0, stream>>>(h2, batch, sums, cnts, N, NWAVES);
    int total = G * 32;
    final_kernel<<<(total + 255) / 256, 256, 0, stream>>>(sums, cnts, lin_w, lin_b, out, total);
}

// Round 2
// 373.997 us; speedup vs baseline: 1.4184x; 1.4184x over previous
//
#include <hip/hip_runtime.h>
#include <math.h>

// ---------------------------------------------------------------------------
// GATv2 x2 + mean-pool + linear, MI355X.
// R1: ILP-4 edge loop in aggregate (break the per-edge serial chain),
//     parallel 3-phase scan (was single-block Hillis-Steele),
//     countdown fill (no `fill` array), fused zeroing of sums/cnts.
// ---------------------------------------------------------------------------

// ---------------- CSR build ----------------
// also zeroes zbuf[0..zn) (sums+cnts, consumed much later in-stream)
__global__ __launch_bounds__(256) void count_deg_kernel(
    const int* __restrict__ dst, int* __restrict__ deg, int E,
    float* __restrict__ zbuf, int zn) {
    int e = blockIdx.x * blockDim.x + threadIdx.x;
    if (e < zn) zbuf[e] = 0.f;
    if (e < E) atomicAdd(&deg[dst[e]], 1);
}

#define SCAN_B 256
// phase 1: per-block sums of deg
__global__ __launch_bounds__(SCAN_B) void block_sum_kernel(
    const int* __restrict__ deg, int* __restrict__ bsum, int n) {
    __shared__ int wsum[4];
    int i = blockIdx.x * SCAN_B + threadIdx.x;
    int v = (i < n) ? deg[i] : 0;
    v += __shfl_down(v, 32);
    v += __shfl_down(v, 16);
    v += __shfl_down(v, 8);
    v += __shfl_down(v, 4);
    v += __shfl_down(v, 2);
    v += __shfl_down(v, 1);
    if ((threadIdx.x & 63) == 0) wsum[threadIdx.x >> 6] = v;
    __syncthreads();
    if (threadIdx.x == 0) bsum[blockIdx.x] = wsum[0] + wsum[1] + wsum[2] + wsum[3];
}

// phase 2: exclusive scan of block sums (nb <= 1024), single block
__global__ __launch_bounds__(1024) void scan_bsum_kernel(int* bsum, int nb) {
    __shared__ int buf[1024];
    int t = threadIdx.x;
    int v = (t < nb) ? bsum[t] : 0;
    buf[t] = v;
    __syncthreads();
    for (int off = 1; off < 1024; off <<= 1) {
        int x = (t >= off) ? buf[t - off] : 0;
        __syncthreads();
        buf[t] += x;
        __syncthreads();
    }
    if (t < nb) bsum[t] = buf[t] - v;  // exclusive
}

// phase 3: re-scan each block, add offset, write rowptr
__global__ __launch_bounds__(SCAN_B) void scan_write_kernel(
    const int* __restrict__ deg, const int* __restrict__ bsum,
    int* __restrict__ rowptr, int n) {
    __shared__ int buf[SCAN_B];
    int i = blockIdx.x * SCAN_B + threadIdx.x;
    int t = threadIdx.x;
    int v = (i < n) ? deg[i] : 0;
    buf[t] = v;
    __syncthreads();
    for (int off = 1; off < SCAN_B; off <<= 1) {
        int x = (t >= off) ? buf[t - off] : 0;
        __syncthreads();
        buf[t] += x;
        __syncthreads();
    }
    if (i < n) rowptr[i + 1] = buf[t] + bsum[blockIdx.x];  // inclusive + offset
    if (i == 0) rowptr[0] = 0;
}

// fill via countdown on deg (deg is consumed; no second zeroed array needed)
__global__ __launch_bounds__(256) void fill_csr_kernel(
    const int* __restrict__ src, const int* __restrict__ dst,
    const int* __restrict__ rowptr, int* __restrict__ deg,
    int* __restrict__ csr_src, int E) {
    int e = blockIdx.x * blockDim.x + threadIdx.x;
    if (e < E) {
        int d = dst[e];
        int rem = atomicSub(&deg[d], 1);         // old value, 1..deg
        csr_src[rowptr[d] + rem - 1] = src[e];
    }
}

// ---------------- dual GEMM: xl = X*Wl + bl, xr = X*Wr + br ----------------
#define GROWS 16
__global__ __launch_bounds__(256) void dual_gemm64_kernel(
    const float* __restrict__ X,
    const float* __restrict__ Wl, const float* __restrict__ bl,
    const float* __restrict__ Wr, const float* __restrict__ br,
    float* __restrict__ xl, float* __restrict__ xr, int n) {
    __shared__ float WlS[64 * 64];
    __shared__ float WrS[64 * 64];
    __shared__ float xS[GROWS * 64];
    int t = threadIdx.x;
    for (int i = t; i < 4096; i += 256) { WlS[i] = Wl[i]; WrS[i] = Wr[i]; }
    int row0 = blockIdx.x * GROWS;
    for (int i = t; i < GROWS * 64; i += 256) {
        int r = row0 + (i >> 6);
        xS[i] = (r < n) ? X[r * 64 + (i & 63)] : 0.f;
    }
    __syncthreads();
    int h  = t & 63;
    int rb = t >> 6;
    float accl[4] = {0.f, 0.f, 0.f, 0.f};
    float accr[4] = {0.f, 0.f, 0.f, 0.f};
    for (int d = 0; d < 64; ++d) {
        float wl = WlS[d * 64 + h];
        float wr = WrS[d * 64 + h];
#pragma unroll
        for (int i = 0; i < 4; ++i) {
            float xv = xS[(rb + 4 * i) * 64 + d];
            accl[i] += xv * wl;
            accr[i] += xv * wr;
        }
    }
    float blv = bl[h], brv = br[h];
#pragma unroll
    for (int i = 0; i < 4; ++i) {
        int r = row0 + rb + 4 * i;
        if (r < n) {
            xl[r * 64 + h] = accl[i] + blv;
            xr[r * 64 + h] = accr[i] + brv;
        }
    }
}

// ---------------- per-dst GATv2 aggregation, online softmax, ILP-4 --------
__global__ __launch_bounds__(256) void gat_aggregate_kernel(
    const float* __restrict__ xl, const float* __restrict__ xr,
    const int* __restrict__ rowptr, const int* __restrict__ csr_src,
    const float* __restrict__ att, const float* __restrict__ bias,
    float* __restrict__ out, int n) {
    int wid  = (blockIdx.x * blockDim.x + threadIdx.x) >> 6;
    int lane = threadIdx.x & 63;
    if (wid >= n) return;
    int d = wid;
    float xr_d  = xr[d * 64 + lane];
    float att_l = att[lane];
    int beg = rowptr[d], end = rowptr[d + 1];
    float m = -INFINITY, s = 0.f, acc = 0.f;
    int p = beg;
    // 4 edges per iteration: independent loads, 4 interleaved reduce chains,
    // one online-softmax rescale per group.
    for (; p + 4 <= end; p += 4) {
        int s0 = csr_src[p],     s1 = csr_src[p + 1];
        int s2 = csr_src[p + 2], s3 = csr_src[p + 3];
        float x0 = xl[s0 * 64 + lane];
        float x1 = xl[s1 * 64 + lane];
        float x2 = xl[s2 * 64 + lane];
        float x3 = xl[s3 * 64 + lane];
        float z, c0, c1, c2, c3;
        z = x0 + xr_d; c0 = ((z > 0.f) ? z : 0.2f * z) * att_l;
        z = x1 + xr_d; c1 = ((z > 0.f) ? z : 0.2f * z) * att_l;
        z = x2 + xr_d; c2 = ((z > 0.f) ? z : 0.2f * z) * att_l;
        z = x3 + xr_d; c3 = ((z > 0.f) ? z : 0.2f * z) * att_l;
#pragma unroll
        for (int sh = 32; sh >= 1; sh >>= 1) {
            c0 += __shfl_xor(c0, sh);
            c1 += __shfl_xor(c1, sh);
            c2 += __shfl_xor(c2, sh);
            c3 += __shfl_xor(c3, sh);
        }
        float mb = fmaxf(fmaxf(c0, c1), fmaxf(c2, c3));
        float mn = fmaxf(m, mb);
        float ra = __expf(m - mn);    // 0 on first group (m=-inf)
        float p0 = __expf(c0 - mn), p1 = __expf(c1 - mn);
        float p2 = __expf(c2 - mn), p3 = __expf(c3 - mn);
        s   = s * ra + ((p0 + p1) + (p2 + p3));
        acc = acc * ra + ((p0 * x0 + p1 * x1) + (p2 * x2 + p3 * x3));
        m   = mn;
    }
    for (; p < end; ++p) {
        int srcn  = csr_src[p];
        float xls = xl[srcn * 64 + lane];
        float z   = xls + xr_d;
        float c   = ((z > 0.f) ? z : 0.2f * z) * att_l;
#pragma unroll
        for (int sh = 32; sh >= 1; sh >>= 1) c += __shfl_xor(c, sh);
        float mn = fmaxf(m, c);
        float ra = __expf(m - mn);
        float cb = __expf(c - mn);
        s   = s * ra + cb;
        acc = acc * ra + cb * xls;
        m   = mn;
    }
    float val = (s > 0.f) ? (acc / s) : 0.f;  // deg-0 node -> 0 (+bias)
    val += bias[lane];
    out[d * 64 + lane] = fmaxf(val, 0.f);     // outer relu
}

// ---------------- mean pool over sorted batch ----------------
__global__ __launch_bounds__(256) void pool_kernel(
    const float* __restrict__ h, const int* __restrict__ batch,
    float* __restrict__ sums, float* __restrict__ cnts, int n, int nwaves) {
    int wid  = (blockIdx.x * blockDim.x + threadIdx.x) >> 6;
    int lane = threadIdx.x & 63;
    int per   = (n + nwaves - 1) / nwaves;
    int start = wid * per;
    int end   = min(n, start + per);
    if (start >= end) return;
    int cur   = batch[start];
    float acc = 0.f, cnt = 0.f;
    for (int i = start; i < end; ++i) {
        int g = batch[i];   // wave-uniform
        if (g != cur) {
            atomicAdd(&sums[cur * 64 + lane], acc);
            if (lane == 0) atomicAdd(&cnts[cur], cnt);
            acc = 0.f; cnt = 0.f; cur = g;
        }
        acc += h[i * 64 + lane];
        cnt += 1.f;
    }
    atomicAdd(&sums[cur * 64 + lane], acc);
    if (lane == 0) atomicAdd(&cnts[cur], cnt);
}

// ---------------- final: out = (sums/cnt) @ lin_w + lin_b ----------------
__global__ __launch_bounds__(256) void final_kernel(
    const float* __restrict__ sums, const float* __restrict__ cnts,
    const float* __restrict__ lin_w, const float* __restrict__ lin_b,
    float* __restrict__ out, int total) {
    int tid = blockIdx.x * blockDim.x + threadIdx.x;
    if (tid >= total) return;
    int g = tid >> 5, o = tid & 31;
    float inv = 1.f / fmaxf(cnts[g], 1.f);
    float a = 0.f;
    for (int h = 0; h < 64; ++h) a += sums[g * 64 + h] * lin_w[h * 32 + o];
    out[tid] = a * inv + lin_b[o];
}

extern "C" void kernel_launch(void* const* d_in, const int* in_sizes, int n_in,
                              void* d_out, int out_size, void* d_ws, size_t ws_size,
                              hipStream_t stream) {
    const float* x     = (const float*)d_in[0];
    const int*   ei    = (const int*)d_in[1];
    const int*   batch = (const int*)d_in[2];
    const float* Wl1   = (const float*)d_in[3];
    const float* bl1   = (const float*)d_in[4];
    const float* Wr1   = (const float*)d_in[5];
    const float* br1   = (const float*)d_in[6];
    const float* att1  = (const float*)d_in[7];
    const float* bias1 = (const float*)d_in[8];
    const float* Wl2   = (const float*)d_in[9];
    const float* bl2   = (const float*)d_in[10];
    const float* Wr2   = (const float*)d_in[11];
    const float* br2   = (const float*)d_in[12];
    const float* att2  = (const float*)d_in[13];
    const float* bias2 = (const float*)d_in[14];
    const float* lin_w = (const float*)d_in[15];
    const float* lin_b = (const float*)d_in[16];
    float* out = (float*)d_out;

    const int N = in_sizes[0] / 64;
    const int E = in_sizes[1] / 2;
    const int G = out_size / 32;
    const int* src = ei;
    const int* dst = ei + E;

    // ---- workspace carve-up (256B-aligned) ----
    char*  ws  = (char*)d_ws;
    size_t off = 0;
    auto alloc = [&](size_t bytes) -> void* {
        void* p = ws + off;
        off += bytes;
        off = (off + 255) & ~(size_t)255;
        return p;
    };
    float* xl      = (float*)alloc((size_t)N * 64 * sizeof(float));
    float* xr      = (float*)alloc((size_t)N * 64 * sizeof(float));
    float* h1      = (float*)alloc((size_t)N * 64 * sizeof(float));
    float* h2      = (float*)alloc((size_t)N * 64 * sizeof(float));
    float* sums    = (float*)alloc((size_t)G * 64 * sizeof(float));  // contiguous
    float* cnts    = (float*)alloc((size_t)G * sizeof(float));       //  with sums
    int*   deg     = (int*)alloc((size_t)N * sizeof(int));
    int*   rowptr  = (int*)alloc((size_t)(N + 1) * sizeof(int));
    int*   bsum    = (int*)alloc((size_t)1024 * sizeof(int));
    int*   csr_src = (int*)alloc((size_t)E * sizeof(int));

    // ---- zeroing: only deg needs a memset; sums/cnts zeroed in count_deg ----
    hipMemsetAsync(deg, 0, (size_t)N * sizeof(int), stream);

    // ---- CSR build (shared by both layers) ----
    int egrid = (E + 255) / 256;
    int nb    = (N + SCAN_B - 1) / SCAN_B;   // 196 for N=50000 (<=1024 req'd)
    count_deg_kernel<<<egrid, 256, 0, stream>>>(dst, deg, E, sums, G * 65);
    block_sum_kernel<<<nb, SCAN_B, 0, stream>>>(deg, bsum, N);
    scan_bsum_kernel<<<1, 1024, 0, stream>>>(bsum, nb);
    scan_write_kernel<<<nb, SCAN_B, 0, stream>>>(deg, bsum, rowptr, N);
    fill_csr_kernel<<<egrid, 256, 0, stream>>>(src, dst, rowptr, deg, csr_src, E);

    int ggrid = (N + GROWS - 1) / GROWS;
    int agrid = (N + 3) / 4;          // 4 waves/block, 1 wave per dst node

    // ---- layer 1 ----
    dual_gemm64_kernel<<<ggrid, 256, 0, stream>>>(x, Wl1, bl1, Wr1, br1, xl, xr, N);
    gat_aggregate_kernel<<<agrid, 256, 0, stream>>>(xl, xr, rowptr, csr_src, att1, bias1, h1, N);

    // ---- layer 2 ----
    dual_gemm64_kernel<<<ggrid, 256, 0, stream>>>(h1, Wl2, bl2, Wr2, br2, xl, xr, N);
    gat_aggregate_kernel<<<agrid, 256, 0, stream>>>(xl, xr, rowptr, csr_src, att2, bias2, h2, N);

    // ---- pool + final linear ----
    const int NWAVES = 1024;
    pool_kernel<<<256, 256, 0, stream>>>(h2, batch, sums, cnts, N, NWAVES);
    int total = G * 32;
    final_kernel<<<(total + 255) / 256, 256, 0, stream>>>(sums, cnts, lin_w, lin_b, out, total);
}